// Round 7
// baseline (272.995 us; speedup 1.0000x reference)
//
#include <hip/hip_runtime.h>

// CTC loss forward, B=256 T=2000 L=100 C=36 (S=201, blank=35).
// FP64 linear-domain alpha recursion, one wave per batch, 4 states per lane.
// Round-6: DEEP prefetch pipeline. Rounds 4/5 both stalled ~300cy/step =
// L3 latency / pipeline-depth (L2 thrashes: 32 blocks x 288KB per XCD).
// Fix: 64-row LDS ring, prefetch distance 56 rows, WAITV(48) per step ->
// ~49 bodies of slack per load, wait never blocks, loop is issue-bound.
//   * neighbor exchange via DPP wave_shr:1 (no DS on the serial chain)
//   * ds_read row t+3 at body t, exp'd at t+2, consumed at t+3
//   * renorm every 32 steps: DPP int-max on f64 hi-words + exact pow2 strip
// Per-frame softmax normalizer factors out; S_Z computed in f32 prologue.

#define BB    256
#define TT    2000
#define LLAB  100
#define CC    36
#define BLANK 35
#define LN2   0.6931471805599453

typedef __attribute__((address_space(1))) const unsigned int* as1_u32p;
typedef __attribute__((address_space(3))) unsigned int* as3_u32p;

__device__ __forceinline__ void async_row_load(const float* g, float* lds) {
  __builtin_amdgcn_global_load_lds((as1_u32p)(const void*)g,
                                   (as3_u32p)(void*)lds, 4, 0, 0);
}

#define WAITV(n) asm volatile("s_waitcnt vmcnt(" #n ")" ::: "memory")

static __device__ __forceinline__ int imax(int a, int b) { return a > b ? a : b; }

// lane i gets lane i-1's value; lane 0 gets 0.  (DPP wave_shr:1, zero-fill)
static __device__ __forceinline__ double dpp_up1(double x) {
  long long v = __double_as_longlong(x);
  int lo = (int)(unsigned int)(v & 0xFFFFFFFFLL);
  int hi = (int)(v >> 32);
  int slo = __builtin_amdgcn_update_dpp(0, lo, 0x138, 0xF, 0xF, true);
  int shi = __builtin_amdgcn_update_dpp(0, hi, 0x138, 0xF, 0xF, true);
  long long r = ((long long)shi << 32) | (long long)(unsigned int)slo;
  return __longlong_as_double(r);
}

// wave-wide int max via DPP, broadcast from lane 63.
static __device__ __forceinline__ int wave_imax(int x) {
  x = imax(x, __builtin_amdgcn_update_dpp(x, x, 0x111, 0xF, 0xF, false));
  x = imax(x, __builtin_amdgcn_update_dpp(x, x, 0x112, 0xF, 0xF, false));
  x = imax(x, __builtin_amdgcn_update_dpp(x, x, 0x114, 0xF, 0xF, false));
  x = imax(x, __builtin_amdgcn_update_dpp(x, x, 0x118, 0xF, 0xF, false));
  x = imax(x, __builtin_amdgcn_update_dpp(x, x, 0x142, 0xA, 0xF, false));
  x = imax(x, __builtin_amdgcn_update_dpp(x, x, 0x143, 0xC, 0xF, false));
  return __builtin_amdgcn_readlane(x, 63);
}

__global__ __launch_bounds__(64) void ctc_fused(
    const float* __restrict__ logits,
    const int*   __restrict__ input_labels,
    const int*   __restrict__ input_len,
    const int*   __restrict__ label_len,
    float*       __restrict__ out)
{
  __shared__ float ring[64][CC];         // 9216 B, row r -> slot r & 63
  __shared__ float sink[40];             // dummy dst for tail issues
  const int b    = blockIdx.x;
  const int lane = threadIdx.x;
  const float* lg = logits + (size_t)b * TT * CC;
  const int ilen = input_len[b];
  const int llen = label_len[b];

  // ---------------- prologue: S_Z = sum of per-frame logsumexp ------------
  float sz = 0.f;
  for (int t = lane; t < TT; t += 64) {
    const float4* r4 = (const float4*)(lg + t * CC);   // 144B row, 16B aligned
    float4 q[9];
#pragma unroll
    for (int i = 0; i < 9; ++i) q[i] = r4[i];
    float m = q[0].x;
#pragma unroll
    for (int i = 0; i < 9; ++i) {
      m = fmaxf(m, q[i].x); m = fmaxf(m, q[i].y);
      m = fmaxf(m, q[i].z); m = fmaxf(m, q[i].w);
    }
    float s = 0.f;
#pragma unroll
    for (int i = 0; i < 9; ++i) {
      s += __expf(q[i].x - m) + __expf(q[i].y - m)
         + __expf(q[i].z - m) + __expf(q[i].w - m);
    }
    float z = m + __logf(s);
    if (t == 0 || t < ilen) sz += z;
  }
#pragma unroll
  for (int o = 32; o; o >>= 1) sz += __shfl_xor(sz, o, 64);
  const float S_Z = sz;

  // ---------------- per-lane static state (states 4l..4l+3) ---------------
  const int* lb = input_labels + b * LLAB;
  const int i0 = 2 * lane, i1 = 2 * lane + 1, im = 2 * lane - 1;
  const int c1 = (i0 < LLAB) ? lb[i0] : 0;            // ext[4l+1]
  const int c3 = (i1 < LLAB) ? lb[i1] : 0;            // ext[4l+3]
  const int cm = (im >= 0 && im < LLAB) ? lb[im] : 0;
  const bool skip1 = (lane >= 1) && (c1 != BLANK) && (c1 != cm);
  const bool skip3 = (c3 != BLANK) && (c3 != c1);
  const int ob = BLANK * 4, o1 = c1 * 4, o3 = c3 * 4; // col byte offsets

  // ---------------- t=0 init ----------------------------------------------
  double a0 = 0.0, a1 = 0.0, a2 = 0.0, a3 = 0.0;
  {
    const char* r0 = (const char*)lg;
    float eb = *(const float*)(r0 + ob);
    float e1 = *(const float*)(r0 + o1);
    if (lane == 0) { a0 = (double)__expf(eb); a1 = (double)__expf(e1); }
  }

  // drain everything; from here vmcnt counts only ring loads
  asm volatile("s_waitcnt vmcnt(0) lgkmcnt(0)" ::: "memory");

  // issue ring prefetch rows 1..56  (56 outstanding, cap is 63)
  for (int r = 1; r <= 56; ++r) {
    if (lane < CC) async_row_load(lg + (size_t)r * CC + lane, &ring[r & 63][0]);
  }

  // pre-loop: rows 1..3 resident; pv for frame 1; reg slots for rows 2,3
  float fb[8], f1[8], f3[8];
  double pv0, pv1, pv3;
  WAITV(53);                      // >=3 retired -> rows 1..3 in LDS
  {
    const char* rp1 = (const char*)&ring[1][0];
    pv0 = (double)__expf(*(const float*)(rp1 + ob));
    pv1 = (double)__expf(*(const float*)(rp1 + o1));
    pv3 = (double)__expf(*(const float*)(rp1 + o3));
    const char* rp2 = (const char*)&ring[2][0];
    fb[2] = *(const float*)(rp2 + ob);
    f1[2] = *(const float*)(rp2 + o1);
    f3[2] = *(const float*)(rp2 + o3);
    const char* rp3 = (const char*)&ring[3][0];
    fb[3] = *(const float*)(rp3 + ob);
    f1[3] = *(const float*)(rp3 + o1);
    f3[3] = *(const float*)(rp3 + o3);
  }

  double n3 = 0.0, n3k = 0.0;     // prev-lane a3 (and skip1-gated copy)
  int Eacc = 0;                   // sum of stripped power-of-2 exponents
  const float* pf = lg + (size_t)57 * CC;     // next row to prefetch
  const float* lgLast = lg + (size_t)(TT - 1) * CC;

  // body for step t = tb + J  (tb % 8 == 1, so reg-ring slots are static):
  //  WAITV(48): issued = t+55, so retired >= t+7 -> rows <= t+3 resident
  //  ds_read row t+3 (exp'd 2 bodies later); issue row t+56 (or dummy)
  //  pv_{t+1} = exp(reg slot row t+1); alpha update with pv_t; n3 = dpp(a3)
#define STEP_BODY(J, T)                                                    \
  {                                                                        \
    WAITV(48);                                                             \
    const char* rp_ = (const char*)&ring[((T) + 3) & 63][0];               \
    fb[((J) + 4) & 7] = *(const float*)(rp_ + ob);                         \
    f1[((J) + 4) & 7] = *(const float*)(rp_ + o1);                         \
    f3[((J) + 4) & 7] = *(const float*)(rp_ + o3);                         \
    {                                                                      \
      int rf_ = (T) + 56;                                                  \
      const float* src_ = (rf_ < TT) ? pf : lgLast;                        \
      float* dst_ = (rf_ < TT) ? &ring[rf_ & 63][0] : &sink[0];            \
      if (lane < CC) async_row_load(src_ + lane, dst_);                    \
      pf += CC;                                                            \
    }                                                                      \
    double q0 = (double)__expf(fb[((J) + 2) & 7]);                         \
    double q1 = (double)__expf(f1[((J) + 2) & 7]);                         \
    double q3 = (double)__expf(f3[((J) + 2) & 7]);                         \
    if ((T) < ilen) {                                                      \
      double g3 = skip3 ? a1 : 0.0;                                        \
      double u0 = (a0 + n3) * pv0;                                         \
      double u1 = (a1 + a0 + n3k) * pv1;                                   \
      double u2 = (a2 + a1) * pv0;        /* pv2 == pv0 (blank) */         \
      double u3 = (a3 + a2 + g3) * pv3;                                    \
      a0 = u0; a1 = u1; a2 = u2; a3 = u3;                                  \
    }                                                                      \
    n3  = dpp_up1(a3);                                                     \
    n3k = skip1 ? n3 : 0.0;                                                \
    pv0 = q0; pv1 = q1; pv3 = q3;                                          \
  }

#define RENORM_CHECK(TB)                                                   \
  if (((TB) & 31) == 25) {                                                 \
    int h0 = (int)(__double_as_longlong(a0) >> 32);                        \
    int h1 = (int)(__double_as_longlong(a1) >> 32);                        \
    int h2 = (int)(__double_as_longlong(a2) >> 32);                        \
    int h3 = (int)(__double_as_longlong(a3) >> 32);                        \
    int ebias = wave_imax(imax(imax(h0, h1), imax(h2, h3))) >> 20;         \
    Eacc += ebias - 1023;                                                  \
    double scale = __longlong_as_double((long long)(2046 - ebias) << 52);  \
    a0 *= scale; a1 *= scale; a2 *= scale; a3 *= scale;                    \
    n3 *= scale; n3k *= scale;                                             \
  }

  // main loop: t = 1..2000 in 250 blocks of 8 (t=2000 body is a no-op update
  // since ilen<=2000; its ds_read touches a stale slot harmlessly)
#pragma unroll 1
  for (int tb = 1; tb <= 1993; tb += 8) {
#pragma unroll
    for (int j = 0; j < 8; ++j) { const int t = tb + j; STEP_BODY(j, t) }
    RENORM_CHECK(tb)
  }

  // drain outstanding ring loads before workgroup teardown
  asm volatile("s_waitcnt vmcnt(0)" ::: "memory");

  // ---------------- finalize ----------------------------------------------
  const int sb  = 4 * lane;
  const int end = 2 * llen;
  const int ep  = (end > 0) ? (end - 1) : 0;
  double contrib = 0.0;
  contrib += ((sb + 0 == end) ? a0 : 0.0) + ((sb + 0 == ep) ? a0 : 0.0);
  contrib += ((sb + 1 == end) ? a1 : 0.0) + ((sb + 1 == ep) ? a1 : 0.0);
  contrib += ((sb + 2 == end) ? a2 : 0.0) + ((sb + 2 == ep) ? a2 : 0.0);
  contrib += ((sb + 3 == end) ? a3 : 0.0) + ((sb + 3 == ep) ? a3 : 0.0);
#pragma unroll
  for (int o = 32; o; o >>= 1) contrib += __shfl_xor(contrib, o, 64);

  if (lane == 0) {
    long long u = __double_as_longlong(contrib);
    int e = (int)((u >> 52) & 0x7FF) - 1023;
    double mant = __longlong_as_double(
        (u & 0xFFFFFFFFFFFFFULL) | 0x3FF0000000000000ULL);
    double lc = (double)e * LN2 + (double)__logf((float)mant);
    double loss = -(lc + (double)Eacc * LN2 - (double)S_Z);
    out[b] = (float)loss;
  }
#undef STEP_BODY
#undef RENORM_CHECK
}

extern "C" void kernel_launch(void* const* d_in, const int* in_sizes, int n_in,
                              void* d_out, int out_size, void* d_ws, size_t ws_size,
                              hipStream_t stream) {
  const float* logits = (const float*)d_in[0];
  const int* labels   = (const int*)d_in[1];
  const int* ilen     = (const int*)d_in[2];
  const int* llen     = (const int*)d_in[3];
  float* out          = (float*)d_out;
  (void)in_sizes; (void)n_in; (void)out_size; (void)d_ws; (void)ws_size;
  hipLaunchKernelGGL(ctc_fused, dim3(BB), dim3(64), 0, stream,
                     logits, labels, ilen, llen, out);
}

// Round 11
// 217.118 us; speedup vs baseline: 1.2574x; 1.2574x over previous
//
#include <hip/hip_runtime.h>

// CTC loss forward, B=256 T=2000 L=100 C=36 (S=201, blank=35).
// FP64 linear-domain alpha recursion, one wave per batch, 4 states per lane.
// Round-11: COMPILER-MANAGED register pipeline. R8-R10's inline-asm loads
// into VGPRs are unsound (async writeback vs. register-allocator live-range
// splits -> memory faults). Instead: plain scalar loads into two 48-reg sets
// (A/B), batch-issued 16 bodies ahead of use, pinned by
// __builtin_amdgcn_sched_barrier(0) so they cannot sink to point-of-use
// (R4's failure). The compiler inserts its own counted vmcnt waits at first
// use and handles spills/endpgm correctly. No LDS, no asm memory ops.
//   * neighbor exchange via DPP wave_shr:1
//   * renorm every 32 steps: DPP int-max on f64 hi-words + exact pow2 strip
// Per-frame softmax normalizer factors out; S_Z computed in f32 prologue.

#define BB    256
#define TT    2000
#define LLAB  100
#define CC    36
#define BLANK 35
#define LN2   0.6931471805599453

static __device__ __forceinline__ int imax(int a, int b) { return a > b ? a : b; }

// lane i gets lane i-1's value; lane 0 gets 0.  (DPP wave_shr:1, zero-fill)
static __device__ __forceinline__ double dpp_up1(double x) {
  long long v = __double_as_longlong(x);
  int lo = (int)(unsigned int)(v & 0xFFFFFFFFLL);
  int hi = (int)(v >> 32);
  int slo = __builtin_amdgcn_update_dpp(0, lo, 0x138, 0xF, 0xF, true);
  int shi = __builtin_amdgcn_update_dpp(0, hi, 0x138, 0xF, 0xF, true);
  long long r = ((long long)shi << 32) | (long long)(unsigned int)slo;
  return __longlong_as_double(r);
}

// wave-wide int max via DPP, broadcast from lane 63.
static __device__ __forceinline__ int wave_imax(int x) {
  x = imax(x, __builtin_amdgcn_update_dpp(x, x, 0x111, 0xF, 0xF, false));
  x = imax(x, __builtin_amdgcn_update_dpp(x, x, 0x112, 0xF, 0xF, false));
  x = imax(x, __builtin_amdgcn_update_dpp(x, x, 0x114, 0xF, 0xF, false));
  x = imax(x, __builtin_amdgcn_update_dpp(x, x, 0x118, 0xF, 0xF, false));
  x = imax(x, __builtin_amdgcn_update_dpp(x, x, 0x142, 0xA, 0xF, false));
  x = imax(x, __builtin_amdgcn_update_dpp(x, x, 0x143, 0xC, 0xF, false));
  return __builtin_amdgcn_readlane(x, 63);
}

__global__ __launch_bounds__(64, 1) void ctc_fused(
    const float* __restrict__ logits,
    const int*   __restrict__ input_labels,
    const int*   __restrict__ input_len,
    const int*   __restrict__ label_len,
    float*       __restrict__ out)
{
  const int b    = blockIdx.x;
  const int lane = threadIdx.x;
  const float* lg = logits + (size_t)b * TT * CC;
  const int ilen = input_len[b];
  const int llen = label_len[b];

  // ---------------- prologue: S_Z = sum of per-frame logsumexp ------------
  float sz = 0.f;
  for (int t = lane; t < TT; t += 64) {
    const float4* r4 = (const float4*)(lg + t * CC);   // 144B row, 16B aligned
    float4 q[9];
#pragma unroll
    for (int i = 0; i < 9; ++i) q[i] = r4[i];
    float m = q[0].x;
#pragma unroll
    for (int i = 0; i < 9; ++i) {
      m = fmaxf(m, q[i].x); m = fmaxf(m, q[i].y);
      m = fmaxf(m, q[i].z); m = fmaxf(m, q[i].w);
    }
    float s = 0.f;
#pragma unroll
    for (int i = 0; i < 9; ++i) {
      s += __expf(q[i].x - m) + __expf(q[i].y - m)
         + __expf(q[i].z - m) + __expf(q[i].w - m);
    }
    float z = m + __logf(s);
    if (t == 0 || t < ilen) sz += z;
  }
#pragma unroll
  for (int o = 32; o; o >>= 1) sz += __shfl_xor(sz, o, 64);
  const float S_Z = sz;

  // ---------------- per-lane static state (states 4l..4l+3) ---------------
  const int* lb = input_labels + b * LLAB;
  const int i0 = 2 * lane, i1 = 2 * lane + 1, im = 2 * lane - 1;
  const int c1 = (i0 < LLAB) ? lb[i0] : 0;            // ext[4l+1]
  const int c3 = (i1 < LLAB) ? lb[i1] : 0;            // ext[4l+3]
  const int cm = (im >= 0 && im < LLAB) ? lb[im] : 0;
  const bool skip1 = (lane >= 1) && (c1 != BLANK) && (c1 != cm);
  const bool skip3 = (c3 != BLANK) && (c3 != c1);

  // ---------------- t=0 init + pv for frame 1 ------------------------------
  double a0 = 0.0, a1 = 0.0, a2 = 0.0, a3 = 0.0;
  {
    float eb = lg[BLANK];
    float e1 = lg[c1];
    if (lane == 0) { a0 = (double)__expf(eb); a1 = (double)__expf(e1); }
  }
  double pv0, pv1, pv3;
  {
    const float* rp = lg + CC;           // row 1
    pv0 = (double)__expf(rp[BLANK]);
    pv1 = (double)__expf(rp[c1]);
    pv3 = (double)__expf(rp[c3]);
  }

  // ---------------- two 16-row register sets, batch-prefetched ------------
  // Set A holds rows t0+1..t0+16 (consumed by bodies t0..t0+15);
  // set B holds rows t0+17..t0+32 (consumed by bodies t0+16..t0+31).
  float Ab[16], A1[16], A3[16];
  float Bb[16], B1[16], B3[16];

  // pre-loop: A = rows 2..17 (consumed starting at body 1)
#pragma unroll
  for (int k = 0; k < 16; ++k) {
    const float* rp = lg + (size_t)(2 + k) * CC;
    Ab[k] = rp[BLANK]; A1[k] = rp[c1]; A3[k] = rp[c3];
  }
  __builtin_amdgcn_sched_barrier(0);   // loads may not sink below this point

  double n3 = 0.0, n3k = 0.0;     // prev-lane a3 (and skip1-gated copy)
  int Eacc = 0;                   // sum of stripped power-of-2 exponents

#define BODY(T, Qb, Q1, Q3)                                                \
  {                                                                        \
    double q0 = (double)__expf(Qb);                                        \
    double q1 = (double)__expf(Q1);                                        \
    double q3 = (double)__expf(Q3);                                        \
    if ((T) < ilen) {                                                      \
      double g3 = skip3 ? a1 : 0.0;                                        \
      double u0 = (a0 + n3) * pv0;                                         \
      double u1 = (a1 + a0 + n3k) * pv1;                                   \
      double u2 = (a2 + a1) * pv0;        /* pv2 == pv0 (blank) */         \
      double u3 = (a3 + a2 + g3) * pv3;                                    \
      a0 = u0; a1 = u1; a2 = u2; a3 = u3;                                  \
    }                                                                      \
    n3  = dpp_up1(a3);                                                     \
    n3k = skip1 ? n3 : 0.0;                                                \
    pv0 = q0; pv1 = q1; pv3 = q3;                                          \
  }

  // outer loop: 32 bodies per iteration, 63 iterations, bodies 1..2016
  // (bodies > 1999 skip their update: t < ilen <= 2000 fails).
#pragma unroll 1
  for (int t0 = 1; t0 <= 1985; t0 += 32) {
    // issue B = rows t0+17..t0+32 (clamped); used 16..31 bodies from now
#pragma unroll
    for (int k = 0; k < 16; ++k) {
      int r = t0 + 17 + k; r = (r < TT) ? r : (TT - 1);
      const float* rp = lg + (size_t)r * CC;
      Bb[k] = rp[BLANK]; B1[k] = rp[c1]; B3[k] = rp[c3];
    }
    __builtin_amdgcn_sched_barrier(0);
    // bodies t0..t0+15 consume A (slot j = row t0+1+j)
#pragma unroll
    for (int j = 0; j < 16; ++j) {
      const int t = t0 + j;
      BODY(t, Ab[j], A1[j], A3[j])
    }
    // issue next A = rows t0+33..t0+48 (clamped); used 16..31 bodies from now
#pragma unroll
    for (int k = 0; k < 16; ++k) {
      int r = t0 + 33 + k; r = (r < TT) ? r : (TT - 1);
      const float* rp = lg + (size_t)r * CC;
      Ab[k] = rp[BLANK]; A1[k] = rp[c1]; A3[k] = rp[c3];
    }
    __builtin_amdgcn_sched_barrier(0);
    // bodies t0+16..t0+31 consume B (slot j = row t0+17+j)
#pragma unroll
    for (int j = 0; j < 16; ++j) {
      const int t = t0 + 16 + j;
      BODY(t, Bb[j], B1[j], B3[j])
    }
    // renorm every 32 bodies: exact power-of-2 exponent strip
    {
      int h0 = (int)(__double_as_longlong(a0) >> 32);
      int h1 = (int)(__double_as_longlong(a1) >> 32);
      int h2 = (int)(__double_as_longlong(a2) >> 32);
      int h3 = (int)(__double_as_longlong(a3) >> 32);
      int ebias = wave_imax(imax(imax(h0, h1), imax(h2, h3))) >> 20;
      Eacc += ebias - 1023;
      double scale = __longlong_as_double((long long)(2046 - ebias) << 52);
      a0 *= scale; a1 *= scale; a2 *= scale; a3 *= scale;
      n3 *= scale; n3k *= scale;
    }
  }

  // ---------------- finalize ----------------------------------------------
  const int sb  = 4 * lane;
  const int end = 2 * llen;
  const int ep  = (end > 0) ? (end - 1) : 0;
  double contrib = 0.0;
  contrib += ((sb + 0 == end) ? a0 : 0.0) + ((sb + 0 == ep) ? a0 : 0.0);
  contrib += ((sb + 1 == end) ? a1 : 0.0) + ((sb + 1 == ep) ? a1 : 0.0);
  contrib += ((sb + 2 == end) ? a2 : 0.0) + ((sb + 2 == ep) ? a2 : 0.0);
  contrib += ((sb + 3 == end) ? a3 : 0.0) + ((sb + 3 == ep) ? a3 : 0.0);
#pragma unroll
  for (int o = 32; o; o >>= 1) contrib += __shfl_xor(contrib, o, 64);

  if (lane == 0) {
    long long u = __double_as_longlong(contrib);
    int e = (int)((u >> 52) & 0x7FF) - 1023;
    double mant = __longlong_as_double(
        (u & 0xFFFFFFFFFFFFFULL) | 0x3FF0000000000000ULL);
    double lc = (double)e * LN2 + (double)__logf((float)mant);
    double loss = -(lc + (double)Eacc * LN2 - (double)S_Z);
    out[b] = (float)loss;
  }
#undef BODY
}

extern "C" void kernel_launch(void* const* d_in, const int* in_sizes, int n_in,
                              void* d_out, int out_size, void* d_ws, size_t ws_size,
                              hipStream_t stream) {
  const float* logits = (const float*)d_in[0];
  const int* labels   = (const int*)d_in[1];
  const int* ilen     = (const int*)d_in[2];
  const int* llen     = (const int*)d_in[3];
  float* out          = (float*)d_out;
  (void)in_sizes; (void)n_in; (void)out_size; (void)d_ws; (void)ws_size;
  hipLaunchKernelGGL(ctc_fused, dim3(BB), dim3(64), 0, stream,
                     logits, labels, ilen, llen, out);
}